// Round 5
// baseline (1458.907 us; speedup 1.0000x reference)
//
#include <hip/hip_runtime.h>

// DualLSTMDecoder: B=256, L=512, E=256, H=128 (4H=512 gates per LSTM).
// R5: fused design, recurrent path now EXACT fp32 (R4's 8.9e-2 = 512-step linear accumulation of
// fixed f16 W_hh rounding bias through f~1 forget-gate integrators; x-GEMM f16 error is zero-mean
// and random-walks -> stays f16 MFMA).
//   prep    : W_ih -> f16 tiled WT [lstm][kc][512][32].
//   fused   : 512 blocks (b,lstm) x 512 thr, 16 chunks x 32 steps.
//             GEMM: MFMA 16x16x32_f16, Gx[32][512] -> LDS (fp32).
//             Recurrence: fp32 k-sliced matvec. Thread j = (wave w, lane l): gates
//             gbase=w*64+(l>>3)*8 .. +8, k-slice s=l&7 -> k in [16s,16s+16). 128 fp32 W_hh VGPRs,
//             4x ds_read_b128 of fp32 h, 3-round keep/send butterfly -> thread j holds gate j.
//             FFN partial per step on wave 0 (fp32), written to yp.
//   combine : out = yp0 + yp1 + b_ffn.
#define B_ 256
#define L_ 512
#define E_ 256
#define H_ 128
#define G4_ 512
#define TC 32
#define NCH 16

typedef _Float16 half8  __attribute__((ext_vector_type(8)));
typedef float   float4v __attribute__((ext_vector_type(4)));
typedef int     int4v   __attribute__((ext_vector_type(4)));
typedef unsigned int uint32;

// ---- workspace layout (bytes), ~1.57 MB (R4 proved >=1.84 MB available) ----
static constexpr size_t WT_OFF = 0;                              // f16 [2][8][512][32]
static constexpr size_t WT_SZ  = (size_t)2 * 8 * 512 * 32 * 2;   // 524288
static constexpr size_t YP_OFF = WT_OFF + WT_SZ;                 // f32 [2][B*L]
static constexpr size_t YP_SZ  = (size_t)2 * B_ * L_ * 4;        // 1048576
static constexpr size_t WS_NEEDED = YP_OFF + YP_SZ;

__device__ __forceinline__ uint32 pkrtn(float lo, float hi) {  // RTN f16 pair
  _Float16 a = (_Float16)lo, b = (_Float16)hi;
  return (uint32)__builtin_bit_cast(unsigned short, a) |
         ((uint32)__builtin_bit_cast(unsigned short, b) << 16);
}

// ---------------- phase 0: W_ih -> f16 tiles ----------------
__global__ void prep(const float* __restrict__ WihH, const float* __restrict__ WihF,
                     unsigned char* __restrict__ ws) {
  int id = blockIdx.x * 256 + threadIdx.x;  // 0..262143 covers WT exactly
  int lstm = id >> 17;
  int r = id & 131071;
  int kc = r >> 14;
  int r2 = r & 16383;
  int n = r2 >> 5, k = r2 & 31;
  const float* src = lstm ? WihF : WihH;
  ((_Float16*)(ws + WT_OFF))[id] = (_Float16)src[n * E_ + kc * 32 + k];
}

// ---------------- fused chunk-GEMM + fp32 recurrence + y-partial ----------------
__global__ __launch_bounds__(512, 2) void fused(
    const float* __restrict__ Xh, const float* __restrict__ Xf,
    const float* __restrict__ WhhH, const float* __restrict__ WhhF,
    const float* __restrict__ bihH, const float* __restrict__ bhhH,
    const float* __restrict__ bihF, const float* __restrict__ bhhF,
    const float* __restrict__ Wffn, unsigned char* __restrict__ ws) {
  const int b = blockIdx.x, lstm = blockIdx.y;
  const int j = threadIdx.x;
  const int lane = j & 63, wave = j >> 6, quad = lane >> 4;
  const int s = lane & 7;  // k-slice
  __shared__ _Float16 Bs[512 * 40];       // W_ih k-tile [n][32], pad 40
  __shared__ _Float16 As[32 * 40];        // X chunk k-tile [m][32]
  __shared__ float GxL[32 * 512];         // chunk pre-activations (fp32)
  __shared__ float gl[512];               // gate values
  __shared__ alignas(16) float hlf[128];  // h state, fp32

  // ---- stationary state ----
  const float* Whh = lstm ? WhhF : WhhH;
  const int gbase = wave * 64 + (lane >> 3) * 8;
  float4v w4[8][4];  // 128 fp32: w4[g][q] = W_hh[gbase+g][s*16+4q .. +4]
#pragma unroll
  for (int g = 0; g < 8; ++g) {
    const float* row = Whh + (size_t)(gbase + g) * H_ + s * 16;
#pragma unroll
    for (int q = 0; q < 4; ++q) w4[g][q] = *(const float4v*)(row + 4 * q);
  }
  const float bias = lstm ? (bihF[j] + bhhF[j]) : (bihH[j] + bhhH[j]);
  float wf0 = 0.f, wf1 = 0.f;
  if (wave == 0) {
    wf0 = Wffn[lstm * 128 + 2 * lane];
    wf1 = Wffn[lstm * 128 + 2 * lane + 1];
  }
  const float* Xb = (lstm ? Xf : Xh) + (size_t)b * L_ * E_;
  const _Float16* WT = (const _Float16*)(ws + WT_OFF) + (size_t)lstm * 8 * 512 * 32;
  float* ypout = (float*)(ws + YP_OFF) + (size_t)lstm * (B_ * L_) + (size_t)b * L_;

  const bool isg = (j >= 256) && (j < 384);              // g-gate (tanh), else sigmoid
  const float kexp = isg ? 2.88539008f : -1.44269504f;   // exp2 scale
  float c = 0.f;
  const int am = j >> 4, ak2 = (j & 15) * 2;  // As staging coords

  for (int ch = 0; ch < NCH; ++ch) {
    // ======== chunk GEMM: GxL[m][n] = X[ch*32+m][:] . W_ih[n][:]  (f16 MFMA) ========
    float4v acc[2][4];
#pragma unroll
    for (int mt = 0; mt < 2; ++mt)
#pragma unroll
      for (int t = 0; t < 4; ++t) acc[mt][t] = (float4v){0.f, 0.f, 0.f, 0.f};
    for (int kc = 0; kc < 8; ++kc) {
      {  // stage A: 32x32, one packed f16 pair per thread
        const float* xp = Xb + (size_t)(ch * TC + am) * E_ + kc * 32 + ak2;
        *(uint32*)&As[am * 40 + ak2] = pkrtn(xp[0], xp[1]);
      }
#pragma unroll
      for (int p = 0; p < 4; ++p) {  // stage B: 2048 granules of 8 f16
        int f8 = p * 512 + j;
        int4v wv = *(const int4v*)(WT + (size_t)kc * 16384 + (size_t)f8 * 8);
        *(int4v*)&Bs[(f8 >> 2) * 40 + (f8 & 3) * 8] = wv;
      }
      __syncthreads();
      half8 a0 = *(const half8*)&As[(lane & 15) * 40 + quad * 8];
      half8 a1 = *(const half8*)&As[((lane & 15) + 16) * 40 + quad * 8];
#pragma unroll
      for (int t = 0; t < 4; ++t) {
        half8 bf = *(const half8*)&Bs[((wave * 4 + t) * 16 + (lane & 15)) * 40 + quad * 8];
        acc[0][t] = __builtin_amdgcn_mfma_f32_16x16x32_f16(a0, bf, acc[0][t], 0, 0, 0);
        acc[1][t] = __builtin_amdgcn_mfma_f32_16x16x32_f16(a1, bf, acc[1][t], 0, 0, 0);
      }
      __syncthreads();
    }
    // epilogue: C layout col=lane&15, row=quad*4+rg  (verified m89/m91)
#pragma unroll
    for (int mt = 0; mt < 2; ++mt)
#pragma unroll
      for (int t = 0; t < 4; ++t) {
        int colb = (wave * 4 + t) * 16 + (lane & 15);
#pragma unroll
        for (int rg = 0; rg < 4; ++rg)
          GxL[(mt * 16 + quad * 4 + rg) * 512 + colb] = acc[mt][t][rg];
      }
    __syncthreads();

    // ======== 32 recurrence steps (fp32 exact) ========
    for (int tl = 0; tl < TC; ++tl) {
      float accv = bias + GxL[tl * 512 + j];
      if (ch | tl) {  // t>0: recurrent term (block-uniform branch)
        float4v hv0 = *(const float4v*)&hlf[s * 16];
        float4v hv1 = *(const float4v*)&hlf[s * 16 + 4];
        float4v hv2 = *(const float4v*)&hlf[s * 16 + 8];
        float4v hv3 = *(const float4v*)&hlf[s * 16 + 12];
        float p[8];
#pragma unroll
        for (int g = 0; g < 8; ++g) {
          float4v v = w4[g][0] * hv0;
          v += w4[g][1] * hv1;
          v += w4[g][2] * hv2;
          v += w4[g][3] * hv3;
          p[g] = (v[0] + v[1]) + (v[2] + v[3]);
        }
        // keep/send butterfly over the 8-lane k-slice group; thread j ends with gate j.
        const bool s0 = (s & 1), s1 = (s & 2), s2 = (s & 4);
        float k0 = s0 ? p[1] : p[0], d0 = s0 ? p[0] : p[1];
        float k1 = s0 ? p[3] : p[2], d1 = s0 ? p[2] : p[3];
        float k2 = s0 ? p[5] : p[4], d2 = s0 ? p[4] : p[5];
        float k3 = s0 ? p[7] : p[6], d3 = s0 ? p[6] : p[7];
        k0 += __shfl_xor(d0, 1);
        k1 += __shfl_xor(d1, 1);
        k2 += __shfl_xor(d2, 1);
        k3 += __shfl_xor(d3, 1);
        float m0 = s1 ? k1 : k0, e0 = s1 ? k0 : k1;
        float m1 = s1 ? k3 : k2, e1 = s1 ? k2 : k3;
        m0 += __shfl_xor(e0, 2);
        m1 += __shfl_xor(e1, 2);
        float f0 = s2 ? m1 : m0, f1 = s2 ? m0 : m1;
        f0 += __shfl_xor(f1, 4);
        accv += f0;
      }
      // gate nonlinearity: sigmoid(x)=1/(1+exp2(-1.4427x)); tanh(x)=1-2/(1+exp2(2.8854x))
      float e = __builtin_amdgcn_exp2f(kexp * accv);
      float r = __builtin_amdgcn_rcpf(1.f + e);
      float gval = isg ? (1.f - 2.f * r) : r;
      gl[j] = gval;
      __syncthreads();
      if (j < H_) {
        float iv = gl[j], fv = gl[j + 128], gg = gl[j + 256], ov = gl[j + 384];
        c = fv * c + iv * gg;
        float e2 = __builtin_amdgcn_exp2f(2.88539008f * c);
        float th = 1.f - 2.f * __builtin_amdgcn_rcpf(1.f + e2);
        hlf[j] = ov * th;
      }
      __syncthreads();
      if (wave == 0) {  // y-half = wf . h (fp32); reads-only of hlf, ordered by next barrier
        float y = wf0 * hlf[2 * lane] + wf1 * hlf[2 * lane + 1];
        y += __shfl_xor(y, 1);
        y += __shfl_xor(y, 2);
        y += __shfl_xor(y, 4);
        y += __shfl_xor(y, 8);
        y += __shfl_xor(y, 16);
        y += __shfl_xor(y, 32);
        if (lane == 0) ypout[ch * TC + tl] = y;
      }
    }
  }
}

// ---------------- combine: out = yp0 + yp1 + b_ffn ----------------
__global__ __launch_bounds__(256) void combine(const unsigned char* __restrict__ ws,
                                               const float* __restrict__ bffn,
                                               float* __restrict__ out) {
  int i = blockIdx.x * 256 + threadIdx.x;  // 0..131071
  const float* yp = (const float*)(ws + YP_OFF);
  out[i] = yp[i] + yp[(size_t)B_ * L_ + i] + bffn[0];
}

extern "C" void kernel_launch(void* const* d_in, const int* in_sizes, int n_in,
                              void* d_out, int out_size, void* d_ws, size_t ws_size,
                              hipStream_t stream) {
  (void)in_sizes; (void)n_in; (void)out_size;
  const float* histX = (const float*)d_in[0];
  const float* futX  = (const float*)d_in[1];
  const float* WihH  = (const float*)d_in[2];
  const float* WhhH  = (const float*)d_in[3];
  const float* bihH  = (const float*)d_in[4];
  const float* bhhH  = (const float*)d_in[5];
  const float* WihF  = (const float*)d_in[6];
  const float* WhhF  = (const float*)d_in[7];
  const float* bihF  = (const float*)d_in[8];
  const float* bhhF  = (const float*)d_in[9];
  const float* Wffn  = (const float*)d_in[10];
  const float* bffn  = (const float*)d_in[11];
  unsigned char* ws = (unsigned char*)d_ws;
  float* out = (float*)d_out;

  if (ws_size < WS_NEEDED) return;  // known-safe: R4 ran with 1.84 MB

  prep<<<1024, 256, 0, stream>>>(WihH, WihF, ws);
  fused<<<dim3(B_, 2), 512, 0, stream>>>(histX, futX, WhhH, WhhF, bihH, bhhH, bihF, bhhF,
                                         Wffn, ws);
  combine<<<512, 256, 0, stream>>>(ws, bffn, out);
}

// Round 6
// 1222.446 us; speedup vs baseline: 1.1934x; 1.1934x over previous
//
#include <hip/hip_runtime.h>

// DualLSTMDecoder: B=256, L=512, E=256, H=128 (4H=512 gates per LSTM).
// R6: recurrence moved to MFMA via split-f16 (hi/lo) compensated GEMM.
//   Block = (batch pair bp, lstm): 128x2 = 256 blocks x 512 thr, 1/CU, single round.
//   Per step: gates[2][512] = h[2][128] @ W_hh^T via MFMA 16x16x32_f16 with M-rows
//   {b0_hi, b1_hi, b0_lo*4096, b1_lo*4096}; B = W_hi and W_lo*4096 (two MFMA chains).
//   gate = acc_hi[r0/r1] + 2^-12*(acc_hi[r2/r3] + acc_lo[r0/r1]) -> ~fp32 precision
//   (R4 showed single-f16 W_hh bias integrates linearly over 512 steps; split kills it).
//   x-GEMM: Gx[16t][2b][512] per chunk, MFMA f16, A/B fragments loaded DIRECT from
//   global (pre-tiled WT -> per-lane contiguous 16B granules), no As/Bs LDS staging.
//   lstm0 blocks write y straight to out; combine adds lstm1 partial + b_ffn.
#define B_ 256
#define L_ 512
#define E_ 256
#define H_ 128
#define G4_ 512
#define TC 16
#define NCH 32

typedef _Float16 half8  __attribute__((ext_vector_type(8)));
typedef float   float4v __attribute__((ext_vector_type(4)));
typedef int     int4v   __attribute__((ext_vector_type(4)));
typedef unsigned int uint32;

// ---- workspace layout (bytes), 1.50 MB  (R4 proved >=1.84 MB available) ----
static constexpr size_t WT_OFF = 0;                             // f16 [2][8][512][32]  (W_ih tiled)
static constexpr size_t WT_SZ  = (size_t)2 * 8 * 512 * 32 * 2;  // 524288
static constexpr size_t WH_OFF = WT_OFF + WT_SZ;                // f16 [2][2sel][4][512][32] (W_hh hi/lo)
static constexpr size_t WH_SZ  = (size_t)2 * 2 * 4 * 512 * 32 * 2;  // 524288
static constexpr size_t YP_OFF = WH_OFF + WH_SZ;                // f32 [B][L]  (lstm1 partial y)
static constexpr size_t YP_SZ  = (size_t)B_ * L_ * 4;           // 524288
static constexpr size_t WS_NEEDED = YP_OFF + YP_SZ;             // 1,572,864

__device__ __forceinline__ int pk16(float lo, float hi) {  // RTZ pack, fine for x
  return __builtin_bit_cast(int, __builtin_amdgcn_cvt_pkrtz(lo, hi));
}

// ---------------- phase 0: weight tiling ----------------
// id < 262144: WT  [lstm][kc8][n][k5] <- f16(W_ih[n][kc*32+k5])
// else       : WHf [lstm][sel][kc4][n][k5] <- sel? f16((w-hi)*4096) : hi,  w = W_hh[n][kc*32+k5]
__global__ void prep(const float* __restrict__ WihH, const float* __restrict__ WihF,
                     const float* __restrict__ WhhH, const float* __restrict__ WhhF,
                     unsigned char* __restrict__ ws) {
  int id = blockIdx.x * 256 + threadIdx.x;  // 0..524287
  if (id < 262144) {
    int lstm = id >> 17;
    int r = id & 131071;
    int kc = r >> 14;
    int r2 = r & 16383;
    int n = r2 >> 5, k5 = r2 & 31;
    const float* src = lstm ? WihF : WihH;
    ((_Float16*)(ws + WT_OFF))[id] = (_Float16)src[n * E_ + kc * 32 + k5];
  } else {
    int id2 = id - 262144;
    int lstm = id2 >> 17;
    int r = id2 & 131071;
    int sel = r >> 16;
    int r2 = r & 65535;
    int kc = r2 >> 14;
    int r3 = r2 & 16383;
    int n = r3 >> 5, k5 = r3 & 31;
    const float* src = lstm ? WhhF : WhhH;
    float wv = src[n * H_ + kc * 32 + k5];
    _Float16 hi = (_Float16)wv;
    _Float16 out = sel ? (_Float16)((wv - (float)hi) * 4096.f) : hi;
    ((_Float16*)(ws + WH_OFF))[id2] = out;
  }
}

// ---------------- fused: x-GEMM + MFMA recurrence + y ----------------
__global__ __launch_bounds__(512, 2) void fused(
    const float* __restrict__ Xh, const float* __restrict__ Xf,
    const float* __restrict__ bihH, const float* __restrict__ bhhH,
    const float* __restrict__ bihF, const float* __restrict__ bhhF,
    const float* __restrict__ Wffn, unsigned char* __restrict__ ws,
    float* __restrict__ out) {
  const int bp = blockIdx.x, lstm = blockIdx.y;
  const int tid = threadIdx.x;
  const int w = tid >> 6, lane = tid & 63, quad = lane >> 4, l15 = lane & 15;
  __shared__ float GxL[TC * 2 * 512];     // [t][b][gate] fp32
  __shared__ float gl[2 * 512];           // gate values [b][gate]
  __shared__ _Float16 hA[16 * 4 * 8];     // [granule gk=k>>3][m:b0hi,b1hi,b0lo,b1lo][8]
  __shared__ float hf32[2 * 128];         // h fp32 for y

  // --- stationary: W_hh fragments (hi/lo), bias, ffn weights ---
  const unsigned char* WH = ws + WH_OFF;
  half8 whh[2][4][4];  // [sel][nt][kc]  (128 VGPRs)
#pragma unroll
  for (int sel = 0; sel < 2; ++sel)
#pragma unroll
    for (int nt = 0; nt < 4; ++nt)
#pragma unroll
      for (int kc = 0; kc < 4; ++kc) {
        size_t byte = (size_t)(((lstm * 2 + sel) * 4 + kc) * 512 + ((w * 4 + nt) * 16 + l15)) * 64 +
                      quad * 16;
        whh[sel][nt][kc] = *(const half8*)(WH + byte);
      }
  float bias4[4];
#pragma unroll
  for (int nt = 0; nt < 4; ++nt) {
    int g = (w * 4 + nt) * 16 + l15;
    bias4[nt] = lstm ? (bihF[g] + bhhF[g]) : (bihH[g] + bhhH[g]);
  }
  const float wf0 = Wffn[lstm * 128 + 2 * lane];
  const float wf1 = Wffn[lstm * 128 + 2 * lane + 1];
  const float* Xb0 = (lstm ? Xf : Xh) + (size_t)(2 * bp) * L_ * E_;
  const float* Xb1 = Xb0 + (size_t)L_ * E_;
  const unsigned char* WT = ws + WT_OFF + (size_t)lstm * 262144;
  float* yp1 = (float*)(ws + YP_OFF);
  float* ypout = (lstm == 0) ? (out + (size_t)(2 * bp) * L_) : (yp1 + (size_t)(2 * bp) * L_);

  const int cb = tid >> 7, cu = tid & 127;  // c/h ownership (tid<256)
  float c = 0.f;
  const float s_lo = 1.f / 4096.f;

  for (int ch = 0; ch < NCH; ++ch) {
    // ======== x-GEMM: Gx[t][b][gate] for this chunk (direct-from-global frags) ========
    float4v ax[2][4];
#pragma unroll
    for (int mt = 0; mt < 2; ++mt)
#pragma unroll
      for (int nt = 0; nt < 4; ++nt) ax[mt][nt] = (float4v){0.f, 0.f, 0.f, 0.f};
    for (int kc = 0; kc < 8; ++kc) {
      const float* xa0 = Xb0 + (size_t)(ch * TC + l15) * E_ + kc * 32 + quad * 8;
      const float* xa1 = Xb1 + (size_t)(ch * TC + l15) * E_ + kc * 32 + quad * 8;
      float4v u0 = *(const float4v*)xa0, u1 = *(const float4v*)(xa0 + 4);
      float4v v0 = *(const float4v*)xa1, v1 = *(const float4v*)(xa1 + 4);
      int4v ai;
      ai[0] = pk16(u0[0], u0[1]); ai[1] = pk16(u0[2], u0[3]);
      ai[2] = pk16(u1[0], u1[1]); ai[3] = pk16(u1[2], u1[3]);
      half8 A0 = __builtin_bit_cast(half8, ai);
      ai[0] = pk16(v0[0], v0[1]); ai[1] = pk16(v0[2], v0[3]);
      ai[2] = pk16(v1[0], v1[1]); ai[3] = pk16(v1[2], v1[3]);
      half8 A1 = __builtin_bit_cast(half8, ai);
#pragma unroll
      for (int nt = 0; nt < 4; ++nt) {
        const unsigned char* bptr =
            WT + (size_t)kc * 32768 + (size_t)((w * 4 + nt) * 16 + l15) * 64 + quad * 16;
        half8 bf = *(const half8*)bptr;
        ax[0][nt] = __builtin_amdgcn_mfma_f32_16x16x32_f16(A0, bf, ax[0][nt], 0, 0, 0);
        ax[1][nt] = __builtin_amdgcn_mfma_f32_16x16x32_f16(A1, bf, ax[1][nt], 0, 0, 0);
      }
    }
    // epilogue: C row=quad*4+rg -> t, col -> gate; GxL[t][b][gate]
#pragma unroll
    for (int mt = 0; mt < 2; ++mt)
#pragma unroll
      for (int nt = 0; nt < 4; ++nt) {
        int colb = (w * 4 + nt) * 16 + l15;
#pragma unroll
        for (int rg = 0; rg < 4; ++rg)
          GxL[((quad * 4 + rg) * 2 + mt) * 512 + colb] = ax[mt][nt][rg];
      }
    __syncthreads();

    // ======== TC recurrence steps ========
    for (int tl = 0; tl < TC; ++tl) {
      float4v r1[4], r2[4];
      const bool t0 = (ch == 0) && (tl == 0);
      if (!t0) {
        half8 hfr[4];
#pragma unroll
        for (int kc = 0; kc < 4; ++kc)
          hfr[kc] = *(const half8*)&hA[((kc * 4 + quad) * 4 + (l15 & 3)) * 8];
#pragma unroll
        for (int nt = 0; nt < 4; ++nt) {
          float4v z = (float4v){0.f, 0.f, 0.f, 0.f};
          float4v a = __builtin_amdgcn_mfma_f32_16x16x32_f16(hfr[0], whh[0][nt][0], z, 0, 0, 0);
          a = __builtin_amdgcn_mfma_f32_16x16x32_f16(hfr[1], whh[0][nt][1], a, 0, 0, 0);
          a = __builtin_amdgcn_mfma_f32_16x16x32_f16(hfr[2], whh[0][nt][2], a, 0, 0, 0);
          a = __builtin_amdgcn_mfma_f32_16x16x32_f16(hfr[3], whh[0][nt][3], a, 0, 0, 0);
          r1[nt] = a;
          float4v bacc = __builtin_amdgcn_mfma_f32_16x16x32_f16(hfr[0], whh[1][nt][0], z, 0, 0, 0);
          bacc = __builtin_amdgcn_mfma_f32_16x16x32_f16(hfr[1], whh[1][nt][1], bacc, 0, 0, 0);
          bacc = __builtin_amdgcn_mfma_f32_16x16x32_f16(hfr[2], whh[1][nt][2], bacc, 0, 0, 0);
          bacc = __builtin_amdgcn_mfma_f32_16x16x32_f16(hfr[3], whh[1][nt][3], bacc, 0, 0, 0);
          r2[nt] = bacc;
        }
      } else {
#pragma unroll
        for (int nt = 0; nt < 4; ++nt) {
          r1[nt] = (float4v){0.f, 0.f, 0.f, 0.f};
          r2[nt] = (float4v){0.f, 0.f, 0.f, 0.f};
        }
      }
      if (quad == 0) {  // rows 0..3 live in quad0's C regs
#pragma unroll
        for (int nt = 0; nt < 4; ++nt) {
          int g = (w * 4 + nt) * 16 + l15;
          int ty = g >> 7;  // 0:i 1:f 2:g 3:o
          float pre0 = r1[nt][0] + s_lo * (r1[nt][2] + r2[nt][0]) + bias4[nt] +
                       GxL[(tl * 2 + 0) * 512 + g];
          float pre1 = r1[nt][1] + s_lo * (r1[nt][3] + r2[nt][1]) + bias4[nt] +
                       GxL[(tl * 2 + 1) * 512 + g];
          float ke = (ty == 2) ? 2.88539008f : -1.44269504f;
          float e0 = __builtin_amdgcn_exp2f(ke * pre0);
          float e1 = __builtin_amdgcn_exp2f(ke * pre1);
          float q0 = __builtin_amdgcn_rcpf(1.f + e0);
          float q1 = __builtin_amdgcn_rcpf(1.f + e1);
          gl[g] = (ty == 2) ? (1.f - 2.f * q0) : q0;
          gl[512 + g] = (ty == 2) ? (1.f - 2.f * q1) : q1;
        }
      }
      __syncthreads();
      if (tid < 256) {  // c/h update: b=cb, unit=cu
        float iv = gl[cb * 512 + cu];
        float fv = gl[cb * 512 + cu + 128];
        float gg = gl[cb * 512 + cu + 256];
        float ov = gl[cb * 512 + cu + 384];
        c = fv * c + iv * gg;
        float e2 = __builtin_amdgcn_exp2f(2.88539008f * c);
        float th = 1.f - 2.f * __builtin_amdgcn_rcpf(1.f + e2);
        float h = ov * th;
        _Float16 hh = (_Float16)h;
        _Float16 hl = (_Float16)((h - (float)hh) * 4096.f);
        int gk = cu >> 3, jj = cu & 7;
        hA[((gk * 4) + cb) * 8 + jj] = hh;
        hA[((gk * 4) + 2 + cb) * 8 + jj] = hl;
        hf32[cb * 128 + cu] = h;
      }
      __syncthreads();
      if (w < 2) {  // y-half for b=w
        float y = wf0 * hf32[w * 128 + 2 * lane] + wf1 * hf32[w * 128 + 2 * lane + 1];
        y += __shfl_xor(y, 1);
        y += __shfl_xor(y, 2);
        y += __shfl_xor(y, 4);
        y += __shfl_xor(y, 8);
        y += __shfl_xor(y, 16);
        y += __shfl_xor(y, 32);
        if (lane == 0) ypout[(size_t)w * L_ + ch * TC + tl] = y;
      }
    }
  }
}

// ---------------- combine: out += yp1 + b_ffn ----------------
__global__ __launch_bounds__(256) void combine(const unsigned char* __restrict__ ws,
                                               const float* __restrict__ bffn,
                                               float* __restrict__ out) {
  int i = blockIdx.x * 256 + threadIdx.x;  // 0..131071
  const float* yp1 = (const float*)(ws + YP_OFF);
  out[i] = out[i] + yp1[i] + bffn[0];
}

extern "C" void kernel_launch(void* const* d_in, const int* in_sizes, int n_in,
                              void* d_out, int out_size, void* d_ws, size_t ws_size,
                              hipStream_t stream) {
  (void)in_sizes; (void)n_in; (void)out_size;
  const float* histX = (const float*)d_in[0];
  const float* futX  = (const float*)d_in[1];
  const float* WihH  = (const float*)d_in[2];
  const float* WhhH  = (const float*)d_in[3];
  const float* bihH  = (const float*)d_in[4];
  const float* bhhH  = (const float*)d_in[5];
  const float* WihF  = (const float*)d_in[6];
  const float* WhhF  = (const float*)d_in[7];
  const float* bihF  = (const float*)d_in[8];
  const float* bhhF  = (const float*)d_in[9];
  const float* Wffn  = (const float*)d_in[10];
  const float* bffn  = (const float*)d_in[11];
  unsigned char* ws = (unsigned char*)d_ws;
  float* out = (float*)d_out;

  if (ws_size < WS_NEEDED) return;  // 1.50 MB, under R4's proven 1.84 MB

  prep<<<2048, 256, 0, stream>>>(WihH, WihF, WhhH, WhhF, ws);
  fused<<<dim3(B_ / 2, 2), 512, 0, stream>>>(histX, futX, bihH, bhhH, bihF, bhhF, Wffn, ws, out);
  combine<<<512, 256, 0, stream>>>(ws, bffn, out);
}

// Round 7
// 1055.612 us; speedup vs baseline: 1.3820x; 1.1580x over previous
//
#include <hip/hip_runtime.h>

// DualLSTMDecoder: B=256, L=512, E=256, H=128 (4H=512 gates per LSTM).
// R7: latency restructure of R6 (which was ~5100 cy/step: per-step y global store forced
// vmcnt(0) barrier drains; 2 LDS round-trips/step because i/f/g/o of a unit lived in
// different waves' C regs).
//   - Gate remap: wave w's 4 B-tiles = types {i,f,g,o} x units [16w,16w+16): after MFMA,
//     quad0 lane l15 holds all 4 gates of unit w*16+l15 (both batches) in registers ->
//     in-register activation + c/h update, c in quad0 VGPRs.
//   - hA (h hi/lo A-frags) double-buffered -> ONE __syncthreads per step.
//   - y: h -> hist LDS; per-chunk 32 dots across 8 waves -> ybuf LDS; single flush at end.
//     No global stores inside the step loop.
//   - Split-f16 W_hh compensation as R6 (hi + 2^-12*(lo-terms)), absmax 1.95e-3 preserved.
#define B_ 256
#define L_ 512
#define E_ 256
#define H_ 128
#define G4_ 512
#define TC 16
#define NCH 32

typedef _Float16 half8  __attribute__((ext_vector_type(8)));
typedef float   float4v __attribute__((ext_vector_type(4)));
typedef int     int4v   __attribute__((ext_vector_type(4)));
typedef unsigned int uint32;

// ---- workspace layout (bytes), 1.50 MB ----
static constexpr size_t WT_OFF = 0;                             // f16 [2][8][512][32]  (W_ih tiled)
static constexpr size_t WT_SZ  = (size_t)2 * 8 * 512 * 32 * 2;
static constexpr size_t WH_OFF = WT_OFF + WT_SZ;                // f16 [2][2sel][4][512][32] (W_hh hi/lo)
static constexpr size_t WH_SZ  = (size_t)2 * 2 * 4 * 512 * 32 * 2;
static constexpr size_t YP_OFF = WH_OFF + WH_SZ;                // f32 [B][L]  (lstm1 partial y)
static constexpr size_t YP_SZ  = (size_t)B_ * L_ * 4;
static constexpr size_t WS_NEEDED = YP_OFF + YP_SZ;             // 1,572,864

__device__ __forceinline__ int pk16(float lo, float hi) {
  return __builtin_bit_cast(int, __builtin_amdgcn_cvt_pkrtz(lo, hi));
}
__device__ __forceinline__ float sigf(float x) {
  return __builtin_amdgcn_rcpf(1.f + __builtin_amdgcn_exp2f(-1.44269504f * x));
}
__device__ __forceinline__ float tanhf_(float x) {
  return 1.f - 2.f * __builtin_amdgcn_rcpf(1.f + __builtin_amdgcn_exp2f(2.88539008f * x));
}

// ---------------- phase 0: weight tiling (unchanged from R6) ----------------
__global__ void prep(const float* __restrict__ WihH, const float* __restrict__ WihF,
                     const float* __restrict__ WhhH, const float* __restrict__ WhhF,
                     unsigned char* __restrict__ ws) {
  int id = blockIdx.x * 256 + threadIdx.x;  // 0..524287
  if (id < 262144) {
    int lstm = id >> 17;
    int r = id & 131071;
    int kc = r >> 14;
    int r2 = r & 16383;
    int n = r2 >> 5, k5 = r2 & 31;
    const float* src = lstm ? WihF : WihH;
    ((_Float16*)(ws + WT_OFF))[id] = (_Float16)src[n * E_ + kc * 32 + k5];
  } else {
    int id2 = id - 262144;
    int lstm = id2 >> 17;
    int r = id2 & 131071;
    int sel = r >> 16;
    int r2 = r & 65535;
    int kc = r2 >> 14;
    int r3 = r2 & 16383;
    int n = r3 >> 5, k5 = r3 & 31;
    const float* src = lstm ? WhhF : WhhH;
    float wv = src[n * H_ + kc * 32 + k5];
    _Float16 hi = (_Float16)wv;
    _Float16 o = sel ? (_Float16)((wv - (float)hi) * 4096.f) : hi;
    ((_Float16*)(ws + WH_OFF))[id2] = o;
  }
}

// ---------------- fused ----------------
__global__ __launch_bounds__(512, 2) void fused(
    const float* __restrict__ Xh, const float* __restrict__ Xf,
    const float* __restrict__ bihH, const float* __restrict__ bhhH,
    const float* __restrict__ bihF, const float* __restrict__ bhhF,
    const float* __restrict__ Wffn, unsigned char* __restrict__ ws,
    float* __restrict__ out) {
  const int bp = blockIdx.x, lstm = blockIdx.y;
  const int tid = threadIdx.x;
  const int w = tid >> 6, lane = tid & 63, quad = lane >> 4, l15 = lane & 15;
  __shared__ float GxL[TC * 2 * 512];          // [t][b][g] fp32, 64 KB
  __shared__ _Float16 hA2[2][512];             // dbuf A-frag src [gk][m][8], 2x1 KB
  __shared__ float hist[TC * 2 * 128];         // h fp32 per step, 16 KB
  __shared__ float ybuf[2 * 512];              // y accum, 4 KB

  // --- stationary: W_hh frags (gate-remapped rows g = nt*128 + w*16 + l15), bias, wf ---
  const int u = w * 16 + l15;  // unit owned by quad0 lane
  const unsigned char* WH = ws + WH_OFF;
  half8 whh[2][4][4];  // [sel][nt=type][kc]
#pragma unroll
  for (int sel = 0; sel < 2; ++sel)
#pragma unroll
    for (int nt = 0; nt < 4; ++nt)
#pragma unroll
      for (int kc = 0; kc < 4; ++kc) {
        size_t byte =
            (size_t)(((lstm * 2 + sel) * 4 + kc) * 512 + (nt * 128 + u)) * 64 + quad * 16;
        whh[sel][nt][kc] = *(const half8*)(WH + byte);
      }
  float bias4[4];
#pragma unroll
  for (int nt = 0; nt < 4; ++nt) {
    int g = nt * 128 + u;
    bias4[nt] = lstm ? (bihF[g] + bhhF[g]) : (bihH[g] + bhhH[g]);
  }
  const float wf0 = Wffn[lstm * 128 + 2 * lane];
  const float wf1 = Wffn[lstm * 128 + 2 * lane + 1];
  const float* Xb0 = (lstm ? Xf : Xh) + (size_t)(2 * bp) * L_ * E_;
  const float* Xb1 = Xb0 + (size_t)L_ * E_;
  const unsigned char* WT = ws + WT_OFF + (size_t)lstm * 262144;
  float* yp1 = (float*)(ws + YP_OFF);
  float* ypout = (lstm == 0) ? (out + (size_t)(2 * bp) * L_) : (yp1 + (size_t)(2 * bp) * L_);

  float c0 = 0.f, c1 = 0.f;  // cell state for unit u (quad0 lanes), b0/b1
  const float s_lo = 1.f / 4096.f;

  for (int ch = 0; ch < NCH; ++ch) {
    // ======== x-GEMM: GxL[t][b][g] (direct-from-global fragments) ========
    float4v ax[2][4];
#pragma unroll
    for (int mt = 0; mt < 2; ++mt)
#pragma unroll
      for (int nt = 0; nt < 4; ++nt) ax[mt][nt] = (float4v){0.f, 0.f, 0.f, 0.f};
#pragma unroll 2
    for (int kc = 0; kc < 8; ++kc) {
      const float* xa0 = Xb0 + (size_t)(ch * TC + l15) * E_ + kc * 32 + quad * 8;
      const float* xa1 = Xb1 + (size_t)(ch * TC + l15) * E_ + kc * 32 + quad * 8;
      float4v u0 = *(const float4v*)xa0, u1 = *(const float4v*)(xa0 + 4);
      float4v v0 = *(const float4v*)xa1, v1 = *(const float4v*)(xa1 + 4);
      int4v ai;
      ai[0] = pk16(u0[0], u0[1]); ai[1] = pk16(u0[2], u0[3]);
      ai[2] = pk16(u1[0], u1[1]); ai[3] = pk16(u1[2], u1[3]);
      half8 A0 = __builtin_bit_cast(half8, ai);
      ai[0] = pk16(v0[0], v0[1]); ai[1] = pk16(v0[2], v0[3]);
      ai[2] = pk16(v1[0], v1[1]); ai[3] = pk16(v1[2], v1[3]);
      half8 A1 = __builtin_bit_cast(half8, ai);
#pragma unroll
      for (int nt = 0; nt < 4; ++nt) {
        const unsigned char* bptr =
            WT + (size_t)kc * 32768 + (size_t)(nt * 128 + u) * 64 + quad * 16;
        half8 bf = *(const half8*)bptr;
        ax[0][nt] = __builtin_amdgcn_mfma_f32_16x16x32_f16(A0, bf, ax[0][nt], 0, 0, 0);
        ax[1][nt] = __builtin_amdgcn_mfma_f32_16x16x32_f16(A1, bf, ax[1][nt], 0, 0, 0);
      }
    }
#pragma unroll
    for (int mt = 0; mt < 2; ++mt)
#pragma unroll
      for (int nt = 0; nt < 4; ++nt) {
        int colg = nt * 128 + u;
#pragma unroll
        for (int rg = 0; rg < 4; ++rg)
          GxL[((quad * 4 + rg) * 2 + mt) * 512 + colg] = ax[mt][nt][rg];
      }
    __syncthreads();

    // ======== TC recurrence steps, ONE barrier each ========
    for (int tl = 0; tl < TC; ++tl) {
      const int st = ch * TC + tl;
      float4v r1[4], r2[4];
      if (st) {
        const _Float16* hAr = hA2[st & 1];
        half8 hfr[4];
#pragma unroll
        for (int kc = 0; kc < 4; ++kc)
          hfr[kc] = *(const half8*)&hAr[((kc * 4 + quad) * 4 + (l15 & 3)) * 8];
#pragma unroll
        for (int nt = 0; nt < 4; ++nt) {
          float4v z = (float4v){0.f, 0.f, 0.f, 0.f};
          float4v a = __builtin_amdgcn_mfma_f32_16x16x32_f16(hfr[0], whh[0][nt][0], z, 0, 0, 0);
          a = __builtin_amdgcn_mfma_f32_16x16x32_f16(hfr[1], whh[0][nt][1], a, 0, 0, 0);
          a = __builtin_amdgcn_mfma_f32_16x16x32_f16(hfr[2], whh[0][nt][2], a, 0, 0, 0);
          a = __builtin_amdgcn_mfma_f32_16x16x32_f16(hfr[3], whh[0][nt][3], a, 0, 0, 0);
          r1[nt] = a;
          float4v bq = __builtin_amdgcn_mfma_f32_16x16x32_f16(hfr[0], whh[1][nt][0], z, 0, 0, 0);
          bq = __builtin_amdgcn_mfma_f32_16x16x32_f16(hfr[1], whh[1][nt][1], bq, 0, 0, 0);
          bq = __builtin_amdgcn_mfma_f32_16x16x32_f16(hfr[2], whh[1][nt][2], bq, 0, 0, 0);
          bq = __builtin_amdgcn_mfma_f32_16x16x32_f16(hfr[3], whh[1][nt][3], bq, 0, 0, 0);
          r2[nt] = bq;
        }
      } else {
#pragma unroll
        for (int nt = 0; nt < 4; ++nt) {
          r1[nt] = (float4v){0.f, 0.f, 0.f, 0.f};
          r2[nt] = (float4v){0.f, 0.f, 0.f, 0.f};
        }
      }
      if (quad == 0) {  // all 4 gates of unit u, both batches, in-register
        float pre[4][2];
#pragma unroll
        for (int nt = 0; nt < 4; ++nt)
#pragma unroll
          for (int b = 0; b < 2; ++b)
            pre[nt][b] = r1[nt][b] + s_lo * (r1[nt][2 + b] + r2[nt][b]) + bias4[nt] +
                         GxL[(tl * 2 + b) * 512 + nt * 128 + u];
        _Float16* hAw = hA2[(st + 1) & 1];
        const int gk = u >> 3, jj = u & 7;
        {
          float iv = sigf(pre[0][0]), fv = sigf(pre[1][0]);
          float gg = tanhf_(pre[2][0]), ov = sigf(pre[3][0]);
          c0 = fv * c0 + iv * gg;
          float h = ov * tanhf_(c0);
          _Float16 hh = (_Float16)h;
          hAw[(gk * 4 + 0) * 8 + jj] = hh;
          hAw[(gk * 4 + 2) * 8 + jj] = (_Float16)((h - (float)hh) * 4096.f);
          hist[(tl * 2 + 0) * 128 + u] = h;
        }
        {
          float iv = sigf(pre[0][1]), fv = sigf(pre[1][1]);
          float gg = tanhf_(pre[2][1]), ov = sigf(pre[3][1]);
          c1 = fv * c1 + iv * gg;
          float h = ov * tanhf_(c1);
          _Float16 hh = (_Float16)h;
          hAw[(gk * 4 + 1) * 8 + jj] = hh;
          hAw[(gk * 4 + 3) * 8 + jj] = (_Float16)((h - (float)hh) * 4096.f);
          hist[(tl * 2 + 1) * 128 + u] = h;
        }
      }
      __syncthreads();
    }

    // ======== per-chunk y phase: 32 dots over 8 waves ========
#pragma unroll
    for (int i = 0; i < 4; ++i) {
      int d = w * 4 + i;
      int tl = d >> 1, b = d & 1;
      float y = wf0 * hist[(tl * 2 + b) * 128 + 2 * lane] +
                wf1 * hist[(tl * 2 + b) * 128 + 2 * lane + 1];
      y += __shfl_xor(y, 1);
      y += __shfl_xor(y, 2);
      y += __shfl_xor(y, 4);
      y += __shfl_xor(y, 8);
      y += __shfl_xor(y, 16);
      y += __shfl_xor(y, 32);
      if (lane == 0) ybuf[b * 512 + ch * TC + tl] = y;
    }
    __syncthreads();  // ybuf/hist/GxL stable before next chunk
  }
  // single flush of y (the only global stores besides combine)
  ypout[tid] = ybuf[tid];
  ypout[512 + tid] = ybuf[512 + tid];
}

// ---------------- combine: out += yp1 + b_ffn ----------------
__global__ __launch_bounds__(256) void combine(const unsigned char* __restrict__ ws,
                                               const float* __restrict__ bffn,
                                               float* __restrict__ out) {
  int i = blockIdx.x * 256 + threadIdx.x;  // 0..131071
  const float* yp1 = (const float*)(ws + YP_OFF);
  out[i] = out[i] + yp1[i] + bffn[0];
}

extern "C" void kernel_launch(void* const* d_in, const int* in_sizes, int n_in,
                              void* d_out, int out_size, void* d_ws, size_t ws_size,
                              hipStream_t stream) {
  (void)in_sizes; (void)n_in; (void)out_size;
  const float* histX = (const float*)d_in[0];
  const float* futX  = (const float*)d_in[1];
  const float* WihH  = (const float*)d_in[2];
  const float* WhhH  = (const float*)d_in[3];
  const float* bihH  = (const float*)d_in[4];
  const float* bhhH  = (const float*)d_in[5];
  const float* WihF  = (const float*)d_in[6];
  const float* WhhF  = (const float*)d_in[7];
  const float* bihF  = (const float*)d_in[8];
  const float* bhhF  = (const float*)d_in[9];
  const float* Wffn  = (const float*)d_in[10];
  const float* bffn  = (const float*)d_in[11];
  unsigned char* ws = (unsigned char*)d_ws;
  float* out = (float*)d_out;

  if (ws_size < WS_NEEDED) return;

  prep<<<2048, 256, 0, stream>>>(WihH, WihF, WhhH, WhhF, ws);
  fused<<<dim3(B_ / 2, 2), 512, 0, stream>>>(histX, futX, bihH, bhhH, bihF, bhhF, Wffn, ws, out);
  combine<<<512, 256, 0, stream>>>(ws, bffn, out);
}